// Round 5
// baseline (537.741 us; speedup 1.0000x reference)
//
#include <hip/hip_runtime.h>
#include <math.h>

#define LL    2048
#define DD    512
#define CD    21
#define CLIPD 10
#define NT    256
#define NB    16       // LL/128 row-blocks
#define KPAD  40       // fallback-path LDS row stride (bf16) -> 2-way alias (free)

typedef __attribute__((ext_vector_type(8))) short bf16x8;
typedef __attribute__((ext_vector_type(4))) float f32x4;

typedef __attribute__((address_space(3))) unsigned int        as3_u32;
typedef const __attribute__((address_space(1))) unsigned int  as1_u32;

__device__ __forceinline__ void dma16(const void* g, void* l) {
    __builtin_amdgcn_global_load_lds((as1_u32*)g, (as3_u32*)l, 16, 0, 0);
}

__device__ __forceinline__ unsigned short bf16_rn(float x) {
    union { float f; unsigned u; } v; v.f = x;
    return (unsigned short)((v.u + 0x7FFFu + ((v.u >> 16) & 1u)) >> 16);
}
__device__ __forceinline__ float bf16_f(unsigned short h) {
    union { float f; unsigned u; } v; v.u = ((unsigned)h) << 16;
    return v.f;
}

// ---------- kernel 0 (fused): fp32 -> bf16 hi/lo tiled planes + kp dots ----------
// Reads key ONCE; writes khi/klo in fragment-major tiled layout and kp[row][c].
// chunk c = (((b*16 + r)*16 + kt)*8 + g)*64 + lane
//   row = r*128 + g*16 + (lane&15),  k = kt*32 + (lane>>4)*8 .. +7
// aff=1 (B==16): batch b handled on XCD b/2 (hw xcd = blockIdx.x % 8), matching
// gemm_pair's job->XCD map so plane reads hit the writing XCD's L2.
__global__ __launch_bounds__(256) void prep_kernel(
    const float* __restrict__ key,     // [B*L, D]
    const float* __restrict__ params,  // [C, D]
    unsigned short* __restrict__ khi,
    unsigned short* __restrict__ klo,
    float*       __restrict__ kp,      // [B*L, C]
    const int aff)
{
    __shared__ float4 pL[CD * (DD / 4)];          // 43 KB -> 3 blocks/CU
    const int t = threadIdx.x;
    for (int idx = t; idx < CD * (DD / 4); idx += 256)
        pL[idx] = ((const float4*)params)[idx];
    __syncthreads();

    int b, rh;
    if (aff) {
        const int x = blockIdx.x & 7;        // hw XCD
        const int k = blockIdx.x >> 3;       // 0..63
        b  = 2 * x + (k >> 5);               // batches 2x, 2x+1 on XCD x
        rh = k & 31;
    } else {
        b  = blockIdx.x >> 5;
        rh = blockIdx.x & 31;
    }
    const int r    = rh >> 1;
    const int half = rh & 1;

    const int lane = t & 63;
    const int gg   = t >> 6;            // 0..3
    const int g    = half * 4 + gg;     // 0..7
    const int l16  = lane & 15;
    const int q    = lane >> 4;         // k-quarter

    const int row = r * 128 + g * 16 + l16;
    const size_t gr = (size_t)b * LL + row;

    float acc[CD];
    #pragma unroll
    for (int c = 0; c < CD; ++c) acc[c] = 0.f;

    for (int kt = 0; kt < DD / 32; ++kt) {
        const int k0 = kt * 32 + q * 8;
        const float4* src = (const float4*)(key + gr * DD + k0);
        const float4 v0 = src[0], v1 = src[1];
        const float vv[8] = {v0.x, v0.y, v0.z, v0.w, v1.x, v1.y, v1.z, v1.w};

        unsigned short h[8], l[8];
        #pragma unroll
        for (int e = 0; e < 8; ++e) {
            h[e] = bf16_rn(vv[e]);
            l[e] = bf16_rn(vv[e] - bf16_f(h[e]));
        }
        const size_t c = ((((size_t)b * 16 + r) * 16 + kt) * 8 + g) * 64 + lane;
        *(bf16x8*)(khi + c * 8) = *(const bf16x8*)h;
        *(bf16x8*)(klo + c * 8) = *(const bf16x8*)l;

        #pragma unroll
        for (int cc = 0; cc < CD; ++cc) {
            const float4 p0 = pL[cc * (DD / 4) + (k0 >> 2)];
            const float4 p1 = pL[cc * (DD / 4) + (k0 >> 2) + 1];
            acc[cc] += vv[0] * p0.x + vv[1] * p0.y + vv[2] * p0.z + vv[3] * p0.w
                     + vv[4] * p1.x + vv[5] * p1.y + vv[6] * p1.z + vv[7] * p1.w;
        }
    }

    // reduce partial dots across the 4 k-quarter lanes (stride 16, 32)
    #pragma unroll
    for (int cc = 0; cc < CD; ++cc) {
        acc[cc] += __shfl_xor(acc[cc], 16);
        acc[cc] += __shfl_xor(acc[cc], 32);
    }
    if (q == 0) {
        #pragma unroll
        for (int cc = 0; cc < CD; ++cc) kp[gr * CD + cc] = acc[cc];
    }
}

// ---------- kernel 1 (fallback only): kp[b][i][c] = dot(key[b][i], params[c]) ----------
__global__ __launch_bounds__(256) void kp_kernel(
    const float* __restrict__ key,     // [B*L, D]
    const float* __restrict__ params,  // [C, D]
    float*       __restrict__ kp)      // [B*L, C]
{
    __shared__ float4 pL[CD * (DD / 4)];          // 43 KB
    const int t = threadIdx.x;
    for (int idx = t; idx < CD * (DD / 4); idx += 256)
        pL[idx] = ((const float4*)params)[idx];
    __syncthreads();

    const int ri = blockIdx.x * 256 + t;
    const float4* k4 = (const float4*)key + (size_t)ri * (DD / 4);

    float acc[CD];
    #pragma unroll
    for (int c = 0; c < CD; ++c) acc[c] = 0.f;

    for (int d = 0; d < DD / 4; ++d) {
        const float4 kv = k4[d];
        #pragma unroll
        for (int c = 0; c < CD; ++c) {
            const float4 pv = pL[c * (DD / 4) + d];
            acc[c] += kv.x * pv.x + kv.y * pv.y + kv.z * pv.z + kv.w * pv.w;
        }
    }
    #pragma unroll
    for (int c = 0; c < CD; ++c) kp[(size_t)ri * CD + c] = acc[c];
}

// ---------- kernel 2 (fast path): unified triangular pair GEMM ----------
// One launch for all 136 pairs/batch. nwg = 136*B = 8*cpx (bijective XCD
// swizzle); with B=16, cpx=272 -> each XCD owns exactly 2 batches, whose
// hi/lo planes were written by prep on the SAME XCD (L2 hits).
// 33.5 KB LDS -> 4 blocks/CU.
// near pairs (|bj-bi|<=1): bias gathered per-element from kp (L2-resident).
// far pairs (bj>=bi+2): rel dist clips -> per-row constant bias.
__global__ __launch_bounds__(NT) void gemm_pair_kernel(
    const unsigned short* __restrict__ khi,  // tiled planes
    const unsigned short* __restrict__ klo,
    const int*   __restrict__ mask,          // [B, L]
    const float* __restrict__ kp,            // [B, L, C]
    float*       __restrict__ out,           // [B, L, L]
    const int cpx)
{
    __shared__ unsigned short tiles[4][4096];   // Ah, Al, Bh, Bl : 8 KB each
    __shared__ float biasA[128];                // far: kp[i0+r, 20]
    __shared__ float biasB[128];                // far: kp[j0+r, 0]
    __shared__ int   maskI[128];

    const int t = threadIdx.x;

    // XCD-bijective swizzle
    const int xcd = blockIdx.x & 7;
    const int job = xcd * cpx + (blockIdx.x >> 3);
    const int bz   = job / 136;
    const int pair = job % 136;

    int bi, bj, nearp;
    if (pair < 31) {            // near: even -> (k,k), odd -> (k,k+1)
        nearp = 1;
        bi = pair >> 1;
        bj = bi + (pair & 1);
    } else {                    // far: bj >= bi+2
        nearp = 0;
        int rem = pair - 31;
        bi = 0;
        while (rem >= 14 - bi) { rem -= 14 - bi; ++bi; }
        bj = bi + 2 + rem;
    }
    const int i0 = bi * 128;
    const int j0 = bj * 128;

    // far: per-row constant bias (visible after first k-loop barrier)
    if (!nearp) {
        if (t < 128) biasA[t]       = kp[((size_t)bz * LL + i0 + t) * CD + 20];
        else         biasB[t - 128] = kp[((size_t)bz * LL + j0 + t - 128) * CD + 0];
    }

    const int lane = t & 63, wave = t >> 6;
    const int wr = wave >> 1, wc = wave & 1;
    const int quad = lane >> 4, l16 = lane & 15;

    // wave w stages plane-tile w: 0=Ah 1=Al 2=Bh 3=Bl
    const unsigned short* plane = (wave & 1) ? klo : khi;
    const int rblk = (wave < 2) ? bi : bj;
    const unsigned short* gbase = plane + ((size_t)bz * 16 + rblk) * 16 * 4096;
    unsigned short* lbase = &tiles[wave][0];

    f32x4 acc[4][4];
    #pragma unroll
    for (int mt = 0; mt < 4; ++mt)
        #pragma unroll
        for (int nt = 0; nt < 4; ++nt)
            acc[mt][nt] = (f32x4){0.f, 0.f, 0.f, 0.f};

    for (int kt = 0; kt < DD / 32; ++kt) {
        const unsigned short* gt = gbase + (size_t)kt * 4096;
        #pragma unroll
        for (int seg = 0; seg < 8; ++seg)
            dma16(gt + seg * 512 + lane * 8, lbase + seg * 512);
        __syncthreads();

        bf16x8 fah[4], fal[4], fbh[4], fbl[4];
        #pragma unroll
        for (int x = 0; x < 4; ++x) {
            const int ga = ((wr * 4 + x) * 64 + lane) * 8;
            const int gb = ((wc * 4 + x) * 64 + lane) * 8;
            fah[x] = *(const bf16x8*)&tiles[0][ga];
            fal[x] = *(const bf16x8*)&tiles[1][ga];
            fbh[x] = *(const bf16x8*)&tiles[2][gb];
            fbl[x] = *(const bf16x8*)&tiles[3][gb];
        }

        #pragma unroll
        for (int mt = 0; mt < 4; ++mt)
            #pragma unroll
            for (int nt = 0; nt < 4; ++nt) {
                acc[mt][nt] = __builtin_amdgcn_mfma_f32_16x16x32_bf16(fah[mt], fbh[nt], acc[mt][nt], 0, 0, 0);
                acc[mt][nt] = __builtin_amdgcn_mfma_f32_16x16x32_bf16(fah[mt], fbl[nt], acc[mt][nt], 0, 0, 0);
                acc[mt][nt] = __builtin_amdgcn_mfma_f32_16x16x32_bf16(fal[mt], fbh[nt], acc[mt][nt], 0, 0, 0);
            }
        __syncthreads();
    }

    const int* maskb = mask + (size_t)bz * LL;

    // ---- epilogue A: (bi,bj) tile ----
    int mkv[4];
    #pragma unroll
    for (int nt = 0; nt < 4; ++nt)
        mkv[nt] = maskb[j0 + wc * 64 + nt * 16 + l16];

    if (nearp) {
        #pragma unroll
        for (int mt = 0; mt < 4; ++mt)
            #pragma unroll
            for (int r = 0; r < 4; ++r) {
                const int li   = wr * 64 + mt * 16 + quad * 4 + r;
                const int grow = i0 + li;
                float* orow = out + ((size_t)bz * LL + grow) * LL;
                const float* kprow = kp + ((size_t)bz * LL + grow) * CD;
                #pragma unroll
                for (int nt = 0; nt < 4; ++nt) {
                    const int col = j0 + wc * 64 + nt * 16 + l16;
                    int rel = col - grow;
                    rel = rel < -CLIPD ? -CLIPD : (rel > CLIPD ? CLIPD : rel);
                    const float v = acc[mt][nt][r] + kprow[rel + CLIPD];
                    orow[col] = mkv[nt] ? -1e20f : v;
                }
            }
    } else {
        #pragma unroll
        for (int mt = 0; mt < 4; ++mt)
            #pragma unroll
            for (int r = 0; r < 4; ++r) {
                const int li   = wr * 64 + mt * 16 + quad * 4 + r;
                const float ba = biasA[li];
                float* orow = out + ((size_t)bz * LL + i0 + li) * LL;
                #pragma unroll
                for (int nt = 0; nt < 4; ++nt) {
                    const int col = j0 + wc * 64 + nt * 16 + l16;
                    orow[col] = mkv[nt] ? -1e20f : (acc[mt][nt][r] + ba);
                }
            }
    }

    // ---- epilogue B: mirrored (bj,bi) tile via LDS transpose ----
    if (bi != bj) {
        if (t < 32) ((int4*)maskI)[t] = ((const int4*)(maskb + i0))[t];
        float (*T)[132] = (float (*)[132])(&tiles[0][0]);   // 32x132 f32 = 16.9 KB

        #pragma unroll
        for (int p = 0; p < 4; ++p) {
            __syncthreads();   // chunk buffer free; maskI visible
            if (wc == (p >> 1)) {
                #pragma unroll
                for (int h = 0; h < 2; ++h) {
                    const int nt = 2 * (p & 1) + h;
                    const int cl = nt * 16 + l16 - 32 * (p & 1);   // 0..31 within chunk
                    #pragma unroll
                    for (int mt = 0; mt < 4; ++mt)
                        *(f32x4*)&T[cl][wr * 64 + mt * 16 + quad * 4] = acc[mt][nt];
                }
            }
            __syncthreads();

            const int rl   = t >> 3;                 // 0..31
            const int mrow = j0 + p * 32 + rl;
            const int c0   = (t & 7) * 16;
            float* orow = out + ((size_t)bz * LL + mrow) * LL + i0;

            if (nearp) {
                const float* kprow = kp + ((size_t)bz * LL + mrow) * CD;
                #pragma unroll
                for (int q = 0; q < 4; ++q) {
                    const int cc = c0 + q * 4;
                    const float4 v = *(const float4*)&T[rl][cc];
                    float vv[4] = {v.x, v.y, v.z, v.w};
                    #pragma unroll
                    for (int e = 0; e < 4; ++e) {
                        const int mcol = i0 + cc + e;
                        int rel = mcol - mrow;
                        rel = rel < -CLIPD ? -CLIPD : (rel > CLIPD ? CLIPD : rel);
                        vv[e] = maskI[cc + e] ? -1e20f : (vv[e] + kprow[rel + CLIPD]);
                    }
                    *(float4*)&orow[cc] = *(const float4*)vv;
                }
            } else {
                const float bB = biasB[p * 32 + rl];
                #pragma unroll
                for (int q = 0; q < 4; ++q) {
                    const int cc = c0 + q * 4;
                    const float4 v = *(const float4*)&T[rl][cc];
                    float vv[4] = {v.x, v.y, v.z, v.w};
                    #pragma unroll
                    for (int e = 0; e < 4; ++e)
                        vv[e] = maskI[cc + e] ? -1e20f : (vv[e] + bB);
                    *(float4*)&orow[cc] = *(const float4*)vv;
                }
            }
        }
    }
}

// ---------- kernel 2 (fallback): in-kernel conversion GEMM ----------
__global__ __launch_bounds__(NT) void gemm_mfma_kernel(
    const float* __restrict__ key,
    const int*   __restrict__ mask,
    const float* __restrict__ kp,
    float*       __restrict__ out)
{
    __shared__ unsigned short Ah[128 * KPAD];
    __shared__ unsigned short Al[128 * KPAD];
    __shared__ unsigned short Bhs[128 * KPAD];
    __shared__ unsigned short Bls[128 * KPAD];
    __shared__ float kps[128 * (CD + 1)];

    const int t  = threadIdx.x;
    const int bz = blockIdx.z;
    const int i0 = blockIdx.y * 128;
    const int j0 = blockIdx.x * 128;

    const float4* keyb4 = (const float4*)(key + (size_t)bz * LL * DD);

    for (int idx = t; idx < 128 * CD; idx += NT) {
        const int i = idx / CD, c = idx % CD;
        kps[i * (CD + 1) + c] = kp[((size_t)bz * LL + i0 + i) * CD + c];
    }

    const int lane = t & 63, wave = t >> 6;
    const int wr = wave >> 1, wc = wave & 1;
    const int quad = lane >> 4, l16 = lane & 15;

    f32x4 acc[4][4];
    #pragma unroll
    for (int mt = 0; mt < 4; ++mt)
        #pragma unroll
        for (int nt = 0; nt < 4; ++nt)
            acc[mt][nt] = (f32x4){0.f, 0.f, 0.f, 0.f};

    for (int kt = 0; kt < DD / 32; ++kt) {
        #pragma unroll
        for (int r = 0; r < 2; ++r) {
            const int flat = t + NT * r;
            const int row  = flat >> 2;
            const int kq2  = flat & 3;
            #pragma unroll
            for (int h = 0; h < 2; ++h) {
                const int kq = kq2 * 2 + h;
                const float4 av = keyb4[(size_t)(i0 + row) * (DD / 4) + kt * 8 + kq];
                const float4 bv = keyb4[(size_t)(j0 + row) * (DD / 4) + kt * 8 + kq];
                ushort4 ah4, al4, bh4, bl4;
                ah4.x = bf16_rn(av.x); al4.x = bf16_rn(av.x - bf16_f(ah4.x));
                ah4.y = bf16_rn(av.y); al4.y = bf16_rn(av.y - bf16_f(ah4.y));
                ah4.z = bf16_rn(av.z); al4.z = bf16_rn(av.z - bf16_f(ah4.z));
                ah4.w = bf16_rn(av.w); al4.w = bf16_rn(av.w - bf16_f(ah4.w));
                bh4.x = bf16_rn(bv.x); bl4.x = bf16_rn(bv.x - bf16_f(bh4.x));
                bh4.y = bf16_rn(bv.y); bl4.y = bf16_rn(bv.y - bf16_f(bh4.y));
                bh4.z = bf16_rn(bv.z); bl4.z = bf16_rn(bv.z - bf16_f(bh4.z));
                bh4.w = bf16_rn(bv.w); bl4.w = bf16_rn(bv.w - bf16_f(bh4.w));
                *(ushort4*)&Ah [row * KPAD + kq * 4] = ah4;
                *(ushort4*)&Al [row * KPAD + kq * 4] = al4;
                *(ushort4*)&Bhs[row * KPAD + kq * 4] = bh4;
                *(ushort4*)&Bls[row * KPAD + kq * 4] = bl4;
            }
        }
        __syncthreads();

        bf16x8 fah[4], fal[4], fbh[4], fbl[4];
        #pragma unroll
        for (int x = 0; x < 4; ++x) {
            const int m = wr * 64 + x * 16 + l16;
            const int n = wc * 64 + x * 16 + l16;
            fah[x] = *(const bf16x8*)&Ah [m * KPAD + quad * 8];
            fal[x] = *(const bf16x8*)&Al [m * KPAD + quad * 8];
            fbh[x] = *(const bf16x8*)&Bhs[n * KPAD + quad * 8];
            fbl[x] = *(const bf16x8*)&Bls[n * KPAD + quad * 8];
        }

        #pragma unroll
        for (int mt = 0; mt < 4; ++mt)
            #pragma unroll
            for (int nt = 0; nt < 4; ++nt) {
                acc[mt][nt] = __builtin_amdgcn_mfma_f32_16x16x32_bf16(fah[mt], fbh[nt], acc[mt][nt], 0, 0, 0);
                acc[mt][nt] = __builtin_amdgcn_mfma_f32_16x16x32_bf16(fah[mt], fbl[nt], acc[mt][nt], 0, 0, 0);
                acc[mt][nt] = __builtin_amdgcn_mfma_f32_16x16x32_bf16(fal[mt], fbh[nt], acc[mt][nt], 0, 0, 0);
            }
        __syncthreads();
    }

    const int* maskb = mask + (size_t)bz * LL;
    int mkv[4];
    #pragma unroll
    for (int nt = 0; nt < 4; ++nt)
        mkv[nt] = maskb[j0 + wc * 64 + nt * 16 + l16];

    #pragma unroll
    for (int mt = 0; mt < 4; ++mt)
        #pragma unroll
        for (int r = 0; r < 4; ++r) {
            const int li   = wr * 64 + mt * 16 + quad * 4 + r;
            const int grow = i0 + li;
            float* orow = out + ((size_t)bz * LL + grow) * LL;
            #pragma unroll
            for (int nt = 0; nt < 4; ++nt) {
                const int col = j0 + wc * 64 + nt * 16 + l16;
                int rel = col - grow;
                rel = rel < -CLIPD ? -CLIPD : (rel > CLIPD ? CLIPD : rel);
                const float v = acc[mt][nt][r] + kps[li * (CD + 1) + rel + CLIPD];
                orow[col] = mkv[nt] ? -1e20f : v;
            }
        }
}

// ---------- kernel 3: in-place row softmax ----------
// aff=1 (B==16): rows of batch b handled on XCD b/2 (hw xcd = blockIdx.x % 8),
// matching gemm_pair's writer XCD -> freshest tiles hit that XCD's L2.
__global__ __launch_bounds__(256) void softmax_kernel(float* __restrict__ out, const int aff) {
    int row;
    if (aff) {
        const int x = blockIdx.x & 7;
        const int s = blockIdx.x >> 3;            // 0..1023
        row = x * 4096 + s * 4 + (threadIdx.x >> 6);
    } else {
        row = blockIdx.x * 4 + (threadIdx.x >> 6);
    }
    const int lane = threadIdx.x & 63;
    float4* r4 = (float4*)out + (size_t)row * (LL / 4);

    float4 v[8];
    float mx = -INFINITY;
    #pragma unroll
    for (int c = 0; c < 8; ++c) {
        v[c] = r4[lane + 64 * c];
        mx = fmaxf(mx, fmaxf(fmaxf(v[c].x, v[c].y), fmaxf(v[c].z, v[c].w)));
    }
    #pragma unroll
    for (int off = 32; off; off >>= 1) mx = fmaxf(mx, __shfl_xor(mx, off));

    float s = 0.f;
    #pragma unroll
    for (int c = 0; c < 8; ++c) {
        v[c].x = __expf(v[c].x - mx); v[c].y = __expf(v[c].y - mx);
        v[c].z = __expf(v[c].z - mx); v[c].w = __expf(v[c].w - mx);
        s += v[c].x + v[c].y + v[c].z + v[c].w;
    }
    #pragma unroll
    for (int off = 32; off; off >>= 1) s += __shfl_xor(s, off);

    const float inv = 1.0f / s;
    #pragma unroll
    for (int c = 0; c < 8; ++c) {
        v[c].x *= inv; v[c].y *= inv; v[c].z *= inv; v[c].w *= inv;
        r4[lane + 64 * c] = v[c];
    }
}

extern "C" void kernel_launch(void* const* d_in, const int* in_sizes, int n_in,
                              void* d_out, int out_size, void* d_ws, size_t ws_size,
                              hipStream_t stream) {
    const float* key    = (const float*)d_in[0];
    const int*   mask   = (const int*)d_in[1];
    const float* params = (const float*)d_in[2];
    float*       out    = (float*)d_out;

    const int B = in_sizes[0] / (LL * DD);        // 16
    const int nrows = B * LL;                     // 32768

    const size_t kp_bytes    = (size_t)nrows * CD * sizeof(float);      // 2.75 MB
    const size_t plane_elems = (size_t)B * LL * DD;                     // 16.8M
    const size_t need        = kp_bytes + 2 * plane_elems * 2;          // ~70 MB

    float* kp = (float*)d_ws;
    const int aff = (B == 16) ? 1 : 0;            // affinity maps assume B=16

    if (ws_size >= need) {
        unsigned short* khi = (unsigned short*)((char*)d_ws + kp_bytes);
        unsigned short* klo = khi + plane_elems;
        prep_kernel<<<dim3(B * 32), dim3(256), 0, stream>>>(key, params, khi, klo, kp, aff);
        gemm_pair_kernel<<<dim3(136 * B), dim3(NT), 0, stream>>>(khi, klo, mask, kp, out, 136 * B / 8);
    } else {
        kp_kernel<<<dim3(nrows / 256), dim3(256), 0, stream>>>(key, params, kp);
        dim3 ggrid(LL / 128, LL / 128, B);        // 16 x 16 x 16
        gemm_mfma_kernel<<<ggrid, dim3(NT), 0, stream>>>(key, mask, kp, out);
    }

    softmax_kernel<<<dim3(nrows / 4), dim3(256), 0, stream>>>(out, aff);
}

// Round 6
// 507.427 us; speedup vs baseline: 1.0597x; 1.0597x over previous
//
#include <hip/hip_runtime.h>
#include <math.h>

#define LL    2048
#define DD    512
#define CD    21
#define CLIPD 10
#define NT    256
#define NB    16       // LL/128 row-blocks
#define KPAD  40       // fallback-path LDS row stride (bf16) -> 2-way alias (free)

typedef __attribute__((ext_vector_type(8))) short bf16x8;
typedef __attribute__((ext_vector_type(4))) float f32x4;

typedef __attribute__((address_space(3))) unsigned int        as3_u32;
typedef const __attribute__((address_space(1))) unsigned int  as1_u32;

__device__ __forceinline__ void dma16(const void* g, void* l) {
    __builtin_amdgcn_global_load_lds((as1_u32*)g, (as3_u32*)l, 16, 0, 0);
}

__device__ __forceinline__ unsigned short bf16_rn(float x) {
    union { float f; unsigned u; } v; v.f = x;
    return (unsigned short)((v.u + 0x7FFFu + ((v.u >> 16) & 1u)) >> 16);
}
__device__ __forceinline__ float bf16_f(unsigned short h) {
    union { float f; unsigned u; } v; v.u = ((unsigned)h) << 16;
    return v.f;
}

// ---------- kernel 0 (fused): fp32 -> bf16 hi/lo tiled planes + kp dots ----------
// Reads key ONCE; writes khi/klo in fragment-major tiled layout and kp[row][c].
// chunk c = (((b*16 + r)*16 + kt)*8 + g)*64 + lane
//   row = r*128 + g*16 + (lane&15),  k = kt*32 + (lane>>4)*8 .. +7
__global__ __launch_bounds__(256) void prep_kernel(
    const float* __restrict__ key,     // [B*L, D]
    const float* __restrict__ params,  // [C, D]
    unsigned short* __restrict__ khi,
    unsigned short* __restrict__ klo,
    float*       __restrict__ kp)      // [B*L, C]
{
    __shared__ float4 pL[CD * (DD / 4)];          // 43 KB -> 3 blocks/CU
    const int t = threadIdx.x;
    for (int idx = t; idx < CD * (DD / 4); idx += 256)
        pL[idx] = ((const float4*)params)[idx];
    __syncthreads();

    const int b    = blockIdx.x >> 5;
    const int rh   = blockIdx.x & 31;
    const int r    = rh >> 1;
    const int half = rh & 1;

    const int lane = t & 63;
    const int gg   = t >> 6;            // 0..3
    const int g    = half * 4 + gg;     // 0..7
    const int l16  = lane & 15;
    const int q    = lane >> 4;         // k-quarter

    const int row = r * 128 + g * 16 + l16;
    const size_t gr = (size_t)b * LL + row;

    float acc[CD];
    #pragma unroll
    for (int c = 0; c < CD; ++c) acc[c] = 0.f;

    for (int kt = 0; kt < DD / 32; ++kt) {
        const int k0 = kt * 32 + q * 8;
        const float4* src = (const float4*)(key + gr * DD + k0);
        const float4 v0 = src[0], v1 = src[1];
        const float vv[8] = {v0.x, v0.y, v0.z, v0.w, v1.x, v1.y, v1.z, v1.w};

        unsigned short h[8], l[8];
        #pragma unroll
        for (int e = 0; e < 8; ++e) {
            h[e] = bf16_rn(vv[e]);
            l[e] = bf16_rn(vv[e] - bf16_f(h[e]));
        }
        const size_t c = ((((size_t)b * 16 + r) * 16 + kt) * 8 + g) * 64 + lane;
        *(bf16x8*)(khi + c * 8) = *(const bf16x8*)h;
        *(bf16x8*)(klo + c * 8) = *(const bf16x8*)l;

        #pragma unroll
        for (int cc = 0; cc < CD; ++cc) {
            const float4 p0 = pL[cc * (DD / 4) + (k0 >> 2)];
            const float4 p1 = pL[cc * (DD / 4) + (k0 >> 2) + 1];
            acc[cc] += vv[0] * p0.x + vv[1] * p0.y + vv[2] * p0.z + vv[3] * p0.w
                     + vv[4] * p1.x + vv[5] * p1.y + vv[6] * p1.z + vv[7] * p1.w;
        }
    }

    // reduce partial dots across the 4 k-quarter lanes (stride 16, 32)
    #pragma unroll
    for (int cc = 0; cc < CD; ++cc) {
        acc[cc] += __shfl_xor(acc[cc], 16);
        acc[cc] += __shfl_xor(acc[cc], 32);
    }
    if (q == 0) {
        #pragma unroll
        for (int cc = 0; cc < CD; ++cc) kp[gr * CD + cc] = acc[cc];
    }
}

// ---------- kernel 1 (fallback only): kp[b][i][c] = dot(key[b][i], params[c]) ----------
__global__ __launch_bounds__(256) void kp_kernel(
    const float* __restrict__ key,     // [B*L, D]
    const float* __restrict__ params,  // [C, D]
    float*       __restrict__ kp)      // [B*L, C]
{
    __shared__ float4 pL[CD * (DD / 4)];          // 43 KB
    const int t = threadIdx.x;
    for (int idx = t; idx < CD * (DD / 4); idx += 256)
        pL[idx] = ((const float4*)params)[idx];
    __syncthreads();

    const int ri = blockIdx.x * 256 + t;
    const float4* k4 = (const float4*)key + (size_t)ri * (DD / 4);

    float acc[CD];
    #pragma unroll
    for (int c = 0; c < CD; ++c) acc[c] = 0.f;

    for (int d = 0; d < DD / 4; ++d) {
        const float4 kv = k4[d];
        #pragma unroll
        for (int c = 0; c < CD; ++c) {
            const float4 pv = pL[c * (DD / 4) + d];
            acc[c] += kv.x * pv.x + kv.y * pv.y + kv.z * pv.z + kv.w * pv.w;
        }
    }
    #pragma unroll
    for (int c = 0; c < CD; ++c) kp[(size_t)ri * CD + c] = acc[c];
}

// ---------- kernel 2 (fast path): unified triangular pair GEMM ----------
// One launch for all 136 pairs/batch. 2176 blocks = 8 XCD x 272 jobs
// (bijective swizzle). 33.5 KB LDS -> 4 blocks/CU.
// near pairs (|bj-bi|<=1): bias gathered per-element from kp (L2-resident).
// far pairs (bj>=bi+2): rel dist clips -> per-row constant bias.
// diagonal pairs (bi==bj): B tile == A tile -> waves 2,3 skip staging and
// B-fragments read from the A planes (halves staged bytes for those blocks).
__global__ __launch_bounds__(NT) void gemm_pair_kernel(
    const unsigned short* __restrict__ khi,  // tiled planes
    const unsigned short* __restrict__ klo,
    const int*   __restrict__ mask,          // [B, L]
    const float* __restrict__ kp,            // [B, L, C]
    float*       __restrict__ out,           // [B, L, L]
    const int cpx)
{
    __shared__ unsigned short tiles[4][4096];   // Ah, Al, Bh, Bl : 8 KB each
    __shared__ float biasA[128];                // far: kp[i0+r, 20]
    __shared__ float biasB[128];                // far: kp[j0+r, 0]
    __shared__ int   maskI[128];

    const int t = threadIdx.x;

    // XCD-bijective swizzle
    const int xcd = blockIdx.x & 7;
    const int job = xcd * cpx + (blockIdx.x >> 3);
    const int bz   = job / 136;
    const int pair = job % 136;

    int bi, bj, nearp;
    if (pair < 31) {            // near: even -> (k,k), odd -> (k,k+1)
        nearp = 1;
        bi = pair >> 1;
        bj = bi + (pair & 1);
    } else {                    // far: bj >= bi+2
        nearp = 0;
        int rem = pair - 31;
        bi = 0;
        while (rem >= 14 - bi) { rem -= 14 - bi; ++bi; }
        bj = bi + 2 + rem;
    }
    const int i0 = bi * 128;
    const int j0 = bj * 128;
    const int diag = (bi == bj);

    // far: per-row constant bias (visible after first k-loop barrier)
    if (!nearp) {
        if (t < 128) biasA[t]       = kp[((size_t)bz * LL + i0 + t) * CD + 20];
        else         biasB[t - 128] = kp[((size_t)bz * LL + j0 + t - 128) * CD + 0];
    }

    const int lane = t & 63, wave = t >> 6;
    const int wr = wave >> 1, wc = wave & 1;
    const int quad = lane >> 4, l16 = lane & 15;

    // wave w stages plane-tile w: 0=Ah 1=Al 2=Bh 3=Bl
    const unsigned short* plane = (wave & 1) ? klo : khi;
    const int rblk = (wave < 2) ? bi : bj;
    const unsigned short* gbase = plane + ((size_t)bz * 16 + rblk) * 16 * 4096;
    unsigned short* lbase = &tiles[wave][0];
    const int do_stage = !(diag && wave >= 2);   // diag: B planes == A planes
    const int bofs = diag ? 0 : 2;               // B-fragment source plane index

    f32x4 acc[4][4];
    #pragma unroll
    for (int mt = 0; mt < 4; ++mt)
        #pragma unroll
        for (int nt = 0; nt < 4; ++nt)
            acc[mt][nt] = (f32x4){0.f, 0.f, 0.f, 0.f};

    for (int kt = 0; kt < DD / 32; ++kt) {
        const unsigned short* gt = gbase + (size_t)kt * 4096;
        if (do_stage) {
            #pragma unroll
            for (int seg = 0; seg < 8; ++seg)
                dma16(gt + seg * 512 + lane * 8, lbase + seg * 512);
        }
        __syncthreads();

        bf16x8 fah[4], fal[4], fbh[4], fbl[4];
        #pragma unroll
        for (int x = 0; x < 4; ++x) {
            const int ga = ((wr * 4 + x) * 64 + lane) * 8;
            const int gb = ((wc * 4 + x) * 64 + lane) * 8;
            fah[x] = *(const bf16x8*)&tiles[0][ga];
            fal[x] = *(const bf16x8*)&tiles[1][ga];
            fbh[x] = *(const bf16x8*)&tiles[bofs][gb];
            fbl[x] = *(const bf16x8*)&tiles[bofs + 1][gb];
        }

        #pragma unroll
        for (int mt = 0; mt < 4; ++mt)
            #pragma unroll
            for (int nt = 0; nt < 4; ++nt) {
                acc[mt][nt] = __builtin_amdgcn_mfma_f32_16x16x32_bf16(fah[mt], fbh[nt], acc[mt][nt], 0, 0, 0);
                acc[mt][nt] = __builtin_amdgcn_mfma_f32_16x16x32_bf16(fah[mt], fbl[nt], acc[mt][nt], 0, 0, 0);
                acc[mt][nt] = __builtin_amdgcn_mfma_f32_16x16x32_bf16(fal[mt], fbh[nt], acc[mt][nt], 0, 0, 0);
            }
        __syncthreads();
    }

    const int* maskb = mask + (size_t)bz * LL;

    // ---- epilogue A: (bi,bj) tile ----
    int mkv[4];
    #pragma unroll
    for (int nt = 0; nt < 4; ++nt)
        mkv[nt] = maskb[j0 + wc * 64 + nt * 16 + l16];

    if (nearp) {
        #pragma unroll
        for (int mt = 0; mt < 4; ++mt)
            #pragma unroll
            for (int r = 0; r < 4; ++r) {
                const int li   = wr * 64 + mt * 16 + quad * 4 + r;
                const int grow = i0 + li;
                float* orow = out + ((size_t)bz * LL + grow) * LL;
                const float* kprow = kp + ((size_t)bz * LL + grow) * CD;
                #pragma unroll
                for (int nt = 0; nt < 4; ++nt) {
                    const int col = j0 + wc * 64 + nt * 16 + l16;
                    int rel = col - grow;
                    rel = rel < -CLIPD ? -CLIPD : (rel > CLIPD ? CLIPD : rel);
                    const float v = acc[mt][nt][r] + kprow[rel + CLIPD];
                    orow[col] = mkv[nt] ? -1e20f : v;
                }
            }
    } else {
        #pragma unroll
        for (int mt = 0; mt < 4; ++mt)
            #pragma unroll
            for (int r = 0; r < 4; ++r) {
                const int li   = wr * 64 + mt * 16 + quad * 4 + r;
                const float ba = biasA[li];
                float* orow = out + ((size_t)bz * LL + i0 + li) * LL;
                #pragma unroll
                for (int nt = 0; nt < 4; ++nt) {
                    const int col = j0 + wc * 64 + nt * 16 + l16;
                    orow[col] = mkv[nt] ? -1e20f : (acc[mt][nt][r] + ba);
                }
            }
    }

    // ---- epilogue B: mirrored (bj,bi) tile via LDS transpose ----
    if (!diag) {
        if (t < 32) ((int4*)maskI)[t] = ((const int4*)(maskb + i0))[t];
        float (*T)[132] = (float (*)[132])(&tiles[0][0]);   // 32x132 f32 = 16.9 KB

        #pragma unroll
        for (int p = 0; p < 4; ++p) {
            __syncthreads();   // chunk buffer free; maskI visible
            if (wc == (p >> 1)) {
                #pragma unroll
                for (int h = 0; h < 2; ++h) {
                    const int nt = 2 * (p & 1) + h;
                    const int cl = nt * 16 + l16 - 32 * (p & 1);   // 0..31 within chunk
                    #pragma unroll
                    for (int mt = 0; mt < 4; ++mt)
                        *(f32x4*)&T[cl][wr * 64 + mt * 16 + quad * 4] = acc[mt][nt];
                }
            }
            __syncthreads();

            const int rl   = t >> 3;                 // 0..31
            const int mrow = j0 + p * 32 + rl;
            const int c0   = (t & 7) * 16;
            float* orow = out + ((size_t)bz * LL + mrow) * LL + i0;

            if (nearp) {
                const float* kprow = kp + ((size_t)bz * LL + mrow) * CD;
                #pragma unroll
                for (int q = 0; q < 4; ++q) {
                    const int cc = c0 + q * 4;
                    const float4 v = *(const float4*)&T[rl][cc];
                    float vv[4] = {v.x, v.y, v.z, v.w};
                    #pragma unroll
                    for (int e = 0; e < 4; ++e) {
                        const int mcol = i0 + cc + e;
                        int rel = mcol - mrow;
                        rel = rel < -CLIPD ? -CLIPD : (rel > CLIPD ? CLIPD : rel);
                        vv[e] = maskI[cc + e] ? -1e20f : (vv[e] + kprow[rel + CLIPD]);
                    }
                    *(float4*)&orow[cc] = *(const float4*)vv;
                }
            } else {
                const float bB = biasB[p * 32 + rl];
                #pragma unroll
                for (int q = 0; q < 4; ++q) {
                    const int cc = c0 + q * 4;
                    const float4 v = *(const float4*)&T[rl][cc];
                    float vv[4] = {v.x, v.y, v.z, v.w};
                    #pragma unroll
                    for (int e = 0; e < 4; ++e)
                        vv[e] = maskI[cc + e] ? -1e20f : (vv[e] + bB);
                    *(float4*)&orow[cc] = *(const float4*)vv;
                }
            }
        }
    }
}

// ---------- kernel 2 (fallback): in-kernel conversion GEMM ----------
__global__ __launch_bounds__(NT) void gemm_mfma_kernel(
    const float* __restrict__ key,
    const int*   __restrict__ mask,
    const float* __restrict__ kp,
    float*       __restrict__ out)
{
    __shared__ unsigned short Ah[128 * KPAD];
    __shared__ unsigned short Al[128 * KPAD];
    __shared__ unsigned short Bhs[128 * KPAD];
    __shared__ unsigned short Bls[128 * KPAD];
    __shared__ float kps[128 * (CD + 1)];

    const int t  = threadIdx.x;
    const int bz = blockIdx.z;
    const int i0 = blockIdx.y * 128;
    const int j0 = blockIdx.x * 128;

    const float4* keyb4 = (const float4*)(key + (size_t)bz * LL * DD);

    for (int idx = t; idx < 128 * CD; idx += NT) {
        const int i = idx / CD, c = idx % CD;
        kps[i * (CD + 1) + c] = kp[((size_t)bz * LL + i0 + i) * CD + c];
    }

    const int lane = t & 63, wave = t >> 6;
    const int wr = wave >> 1, wc = wave & 1;
    const int quad = lane >> 4, l16 = lane & 15;

    f32x4 acc[4][4];
    #pragma unroll
    for (int mt = 0; mt < 4; ++mt)
        #pragma unroll
        for (int nt = 0; nt < 4; ++nt)
            acc[mt][nt] = (f32x4){0.f, 0.f, 0.f, 0.f};

    for (int kt = 0; kt < DD / 32; ++kt) {
        #pragma unroll
        for (int r = 0; r < 2; ++r) {
            const int flat = t + NT * r;
            const int row  = flat >> 2;
            const int kq2  = flat & 3;
            #pragma unroll
            for (int h = 0; h < 2; ++h) {
                const int kq = kq2 * 2 + h;
                const float4 av = keyb4[(size_t)(i0 + row) * (DD / 4) + kt * 8 + kq];
                const float4 bv = keyb4[(size_t)(j0 + row) * (DD / 4) + kt * 8 + kq];
                ushort4 ah4, al4, bh4, bl4;
                ah4.x = bf16_rn(av.x); al4.x = bf16_rn(av.x - bf16_f(ah4.x));
                ah4.y = bf16_rn(av.y); al4.y = bf16_rn(av.y - bf16_f(ah4.y));
                ah4.z = bf16_rn(av.z); al4.z = bf16_rn(av.z - bf16_f(ah4.z));
                ah4.w = bf16_rn(av.w); al4.w = bf16_rn(av.w - bf16_f(ah4.w));
                bh4.x = bf16_rn(bv.x); bl4.x = bf16_rn(bv.x - bf16_f(bh4.x));
                bh4.y = bf16_rn(bv.y); bl4.y = bf16_rn(bv.y - bf16_f(bh4.y));
                bh4.z = bf16_rn(bv.z); bl4.z = bf16_rn(bv.z - bf16_f(bh4.z));
                bh4.w = bf16_rn(bv.w); bl4.w = bf16_rn(bv.w - bf16_f(bh4.w));
                *(ushort4*)&Ah [row * KPAD + kq * 4] = ah4;
                *(ushort4*)&Al [row * KPAD + kq * 4] = al4;
                *(ushort4*)&Bhs[row * KPAD + kq * 4] = bh4;
                *(ushort4*)&Bls[row * KPAD + kq * 4] = bl4;
            }
        }
        __syncthreads();

        bf16x8 fah[4], fal[4], fbh[4], fbl[4];
        #pragma unroll
        for (int x = 0; x < 4; ++x) {
            const int m = wr * 64 + x * 16 + l16;
            const int n = wc * 64 + x * 16 + l16;
            fah[x] = *(const bf16x8*)&Ah [m * KPAD + quad * 8];
            fal[x] = *(const bf16x8*)&Al [m * KPAD + quad * 8];
            fbh[x] = *(const bf16x8*)&Bhs[n * KPAD + quad * 8];
            fbl[x] = *(const bf16x8*)&Bls[n * KPAD + quad * 8];
        }

        #pragma unroll
        for (int mt = 0; mt < 4; ++mt)
            #pragma unroll
            for (int nt = 0; nt < 4; ++nt) {
                acc[mt][nt] = __builtin_amdgcn_mfma_f32_16x16x32_bf16(fah[mt], fbh[nt], acc[mt][nt], 0, 0, 0);
                acc[mt][nt] = __builtin_amdgcn_mfma_f32_16x16x32_bf16(fah[mt], fbl[nt], acc[mt][nt], 0, 0, 0);
                acc[mt][nt] = __builtin_amdgcn_mfma_f32_16x16x32_bf16(fal[mt], fbh[nt], acc[mt][nt], 0, 0, 0);
            }
        __syncthreads();
    }

    const int* maskb = mask + (size_t)bz * LL;
    int mkv[4];
    #pragma unroll
    for (int nt = 0; nt < 4; ++nt)
        mkv[nt] = maskb[j0 + wc * 64 + nt * 16 + l16];

    #pragma unroll
    for (int mt = 0; mt < 4; ++mt)
        #pragma unroll
        for (int r = 0; r < 4; ++r) {
            const int li   = wr * 64 + mt * 16 + quad * 4 + r;
            const int grow = i0 + li;
            float* orow = out + ((size_t)bz * LL + grow) * LL;
            #pragma unroll
            for (int nt = 0; nt < 4; ++nt) {
                const int col = j0 + wc * 64 + nt * 16 + l16;
                int rel = col - grow;
                rel = rel < -CLIPD ? -CLIPD : (rel > CLIPD ? CLIPD : rel);
                const float v = acc[mt][nt][r] + kps[li * (CD + 1) + rel + CLIPD];
                orow[col] = mkv[nt] ? -1e20f : v;
            }
        }
}

// ---------- kernel 3: in-place row softmax ----------
__global__ __launch_bounds__(256) void softmax_kernel(float* __restrict__ out) {
    const int row  = blockIdx.x * 4 + (threadIdx.x >> 6);
    const int lane = threadIdx.x & 63;
    float4* r4 = (float4*)out + (size_t)row * (LL / 4);

    float4 v[8];
    float mx = -INFINITY;
    #pragma unroll
    for (int c = 0; c < 8; ++c) {
        v[c] = r4[lane + 64 * c];
        mx = fmaxf(mx, fmaxf(fmaxf(v[c].x, v[c].y), fmaxf(v[c].z, v[c].w)));
    }
    #pragma unroll
    for (int off = 32; off; off >>= 1) mx = fmaxf(mx, __shfl_xor(mx, off));

    float s = 0.f;
    #pragma unroll
    for (int c = 0; c < 8; ++c) {
        v[c].x = __expf(v[c].x - mx); v[c].y = __expf(v[c].y - mx);
        v[c].z = __expf(v[c].z - mx); v[c].w = __expf(v[c].w - mx);
        s += v[c].x + v[c].y + v[c].z + v[c].w;
    }
    #pragma unroll
    for (int off = 32; off; off >>= 1) s += __shfl_xor(s, off);

    const float inv = 1.0f / s;
    #pragma unroll
    for (int c = 0; c < 8; ++c) {
        v[c].x *= inv; v[c].y *= inv; v[c].z *= inv; v[c].w *= inv;
        r4[lane + 64 * c] = v[c];
    }
}

extern "C" void kernel_launch(void* const* d_in, const int* in_sizes, int n_in,
                              void* d_out, int out_size, void* d_ws, size_t ws_size,
                              hipStream_t stream) {
    const float* key    = (const float*)d_in[0];
    const int*   mask   = (const int*)d_in[1];
    const float* params = (const float*)d_in[2];
    float*       out    = (float*)d_out;

    const int B = in_sizes[0] / (LL * DD);        // 16
    const int nrows = B * LL;                     // 32768

    const size_t kp_bytes    = (size_t)nrows * CD * sizeof(float);      // 2.75 MB
    const size_t plane_elems = (size_t)B * LL * DD;                     // 16.8M
    const size_t need        = kp_bytes + 2 * plane_elems * 2;          // ~70 MB

    float* kp = (float*)d_ws;

    if (ws_size >= need) {
        unsigned short* khi = (unsigned short*)((char*)d_ws + kp_bytes);
        unsigned short* klo = khi + plane_elems;
        prep_kernel<<<dim3(B * 32), dim3(256), 0, stream>>>(key, params, khi, klo, kp);
        gemm_pair_kernel<<<dim3(136 * B), dim3(NT), 0, stream>>>(khi, klo, mask, kp, out, 136 * B / 8);
    } else {
        kp_kernel<<<dim3(nrows / 256), dim3(256), 0, stream>>>(key, params, kp);
        dim3 ggrid(LL / 128, LL / 128, B);        // 16 x 16 x 16
        gemm_mfma_kernel<<<ggrid, dim3(NT), 0, stream>>>(key, mask, kp, out);
    }

    softmax_kernel<<<dim3(nrows / 4), dim3(256), 0, stream>>>(out);
}